// Round 4
// baseline (31.877 us; speedup 1.0000x reference)
//
#include <hip/hip_runtime.h>
#include <cmath>

#define NROWS 524288
#define NBLOCKS (NROWS / 256)
#define EPS 1e-10f

typedef float f4 __attribute__((ext_vector_type(4)));

__device__ __forceinline__ void glds16(const float* gp, float* lp) {
    // async global->LDS DMA, 16B per lane; LDS dest = wave-uniform base + lane*16
    __builtin_amdgcn_global_load_lds(
        (const __attribute__((address_space(1))) void*)(gp),
        (__attribute__((address_space(3))) void*)(lp), 16, 0, 0);
}

template <int N>
__device__ __forceinline__ float head_loss(const float* x, const float* lbl) {
    float m = -INFINITY;
    #pragma unroll
    for (int i = 0; i < N; ++i) m = fmaxf(m, x[i]);
    float e[N];
    float s = 0.f;
    #pragma unroll
    for (int i = 0; i < N; ++i) { e[i] = __expf(x[i] - m); s += e[i]; }
    float inv = 1.0f / s;
    float acc = 0.f;
    #pragma unroll
    for (int i = 0; i < N; ++i) acc += __logf(e[i] * inv + EPS) * lbl[i];
    return -acc;
}

// LDS: 256*(29+9+6+6)*4 = 51200 B -> 3 blocks/CU (12 waves).
// All strided arrays staged wave-privately (no block barrier before compute).
__global__ __launch_bounds__(256) void fused_loss_kernel(
    const float* __restrict__ o1, const float* __restrict__ o2,
    const float* __restrict__ o3, const float* __restrict__ o4,
    const float* __restrict__ lbl, double* __restrict__ partial) {
    __shared__ float slbl[256 * 29];   // 29696 B
    __shared__ float so4[256 * 9];     //  9216 B
    __shared__ float so2[256 * 6];     //  6144 B
    __shared__ float so3[256 * 6];     //  6144 B
    __shared__ double sacc[4];

    const int tid = threadIdx.x;
    const int wid = tid >> 6;
    const int lane = tid & 63;
    const size_t blk = blockIdx.x;

    // Wave-private sub-block bases (all 16B-aligned: 7424/2304/1536 B per wave)
    const float* gl  = lbl + (blk * 1856 + (size_t)wid * 464) * 4;  // 464 f4/wave
    const float* g4  = o4  + (blk * 576  + (size_t)wid * 144) * 4;  // 144 f4/wave
    const float* g2  = o2  + (blk * 384  + (size_t)wid * 96)  * 4;  //  96 f4/wave
    const float* g3  = o3  + (blk * 384  + (size_t)wid * 96)  * 4;
    float* ll = slbl + (size_t)wid * 464 * 4;
    float* l4 = so4  + (size_t)wid * 144 * 4;
    float* l2 = so2  + (size_t)wid * 96 * 4;
    float* l3 = so3  + (size_t)wid * 96 * 4;

    // Uniform-count DMA staging: 11 async global_load_lds per thread
    #pragma unroll
    for (int k = 0; k < 7; ++k) glds16(gl + (lane + 64 * k) * 4, ll + k * 256);
    #pragma unroll
    for (int k = 0; k < 2; ++k) glds16(g4 + (lane + 64 * k) * 4, l4 + k * 256);
    glds16(g2 + lane * 4, l2);
    glds16(g3 + lane * 4, l3);

    // Tails: reg-staged under predication (ds_write ordering handled by compiler)
    if (lane < 16) {
        f4 t = reinterpret_cast<const f4*>(gl)[448 + lane];
        reinterpret_cast<f4*>(ll)[448 + lane] = t;
        f4 u = reinterpret_cast<const f4*>(g4)[128 + lane];
        reinterpret_cast<f4*>(l4)[128 + lane] = u;
    }
    if (lane < 32) {
        f4 t = reinterpret_cast<const f4*>(g2)[64 + lane];
        reinterpret_cast<f4*>(l2)[64 + lane] = t;
        f4 u = reinterpret_cast<const f4*>(g3)[64 + lane];
        reinterpret_cast<f4*>(l3)[64 + lane] = u;
    }

    // head 1 direct: 8 floats, 32B stride, 16B aligned -> two float4 (line-perfect)
    const size_t i = blk * 256 + tid;
    float v1[8];
    {
        const f4* p = reinterpret_cast<const f4*>(o1 + i * 8);
        f4 a = p[0], b = p[1];
        v1[0] = a.x; v1[1] = a.y; v1[2] = a.z; v1[3] = a.w;
        v1[4] = b.x; v1[5] = b.y; v1[6] = b.z; v1[7] = b.w;
    }

    // Wait for the DMA (compiler cannot see global_load_lds -> ds_read dep)
    asm volatile("s_waitcnt vmcnt(0)" ::: "memory");
    __builtin_amdgcn_sched_barrier(0);

    const float* lrow = slbl + tid * 29;  // stride 29 (odd): 2-way alias, free
    const float* r4   = so4 + tid * 9;    // stride 9 (odd): free
    const float* r2   = so2 + tid * 6;
    const float* r3   = so3 + tid * 6;

    float loss;
    loss  = head_loss<8>(v1, lrow + 0);
    loss += head_loss<6>(r2, lrow + 8);
    loss += head_loss<6>(r3, lrow + 14);
    loss += head_loss<9>(r4, lrow + 20);

    // wave64 shfl reduce in double -> LDS -> per-block partial (no atomics)
    double d = (double)loss;
    #pragma unroll
    for (int off = 32; off > 0; off >>= 1) d += __shfl_down(d, off);

    if (lane == 0) sacc[wid] = d;
    __syncthreads();
    if (tid == 0) partial[blk] = sacc[0] + sacc[1] + sacc[2] + sacc[3];
}

__global__ __launch_bounds__(256) void reduce_kernel(const double* __restrict__ partial,
                                                     float* __restrict__ out) {
    double s = 0.0;
    for (int i = threadIdx.x; i < NBLOCKS; i += 256) s += partial[i];
    #pragma unroll
    for (int off = 32; off > 0; off >>= 1) s += __shfl_down(s, off);
    __shared__ double sa[4];
    const int wid = threadIdx.x >> 6;
    if ((threadIdx.x & 63) == 0) sa[wid] = s;
    __syncthreads();
    if (threadIdx.x == 0) out[0] = (float)((sa[0] + sa[1] + sa[2] + sa[3]) / (double)NROWS);
}

extern "C" void kernel_launch(void* const* d_in, const int* in_sizes, int n_in,
                              void* d_out, int out_size, void* d_ws, size_t ws_size,
                              hipStream_t stream) {
    const float* o1  = (const float*)d_in[0];
    const float* o2  = (const float*)d_in[1];
    const float* o3  = (const float*)d_in[2];
    const float* o4  = (const float*)d_in[3];
    const float* lbl = (const float*)d_in[4];
    double* partial = (double*)d_ws;  // NBLOCKS doubles, fully overwritten each call

    fused_loss_kernel<<<NBLOCKS, 256, 0, stream>>>(o1, o2, o3, o4, lbl, partial);
    reduce_kernel<<<1, 256, 0, stream>>>(partial, (float*)d_out);
}